// Round 15
// baseline (975.835 us; speedup 1.0000x reference)
//
#include <hip/hip_runtime.h>
#include <stdint.h>

// ---------- types / helpers ----------
typedef __bf16 bf16x8 __attribute__((ext_vector_type(8)));
typedef unsigned short ushort8 __attribute__((ext_vector_type(8)));
typedef float floatx4 __attribute__((ext_vector_type(4)));

__device__ __forceinline__ unsigned short f2b(float f) {
    unsigned int u = __builtin_bit_cast(unsigned int, f);
    u += 0x7fffu + ((u >> 16) & 1u);
    return (unsigned short)(u >> 16);
}
__device__ __forceinline__ float b2f(unsigned short u) {
    union { unsigned int i; float f; } x; x.i = ((unsigned int)u) << 16; return x.f;
}
// async global->LDS, 16B per lane; dest must be wave-uniform base + lane*16.
__device__ __forceinline__ void gl_lds16(const unsigned short* g, unsigned short* l) {
    __builtin_amdgcn_global_load_lds(
        (const __attribute__((address_space(1))) unsigned int*)g,
        (__attribute__((address_space(3))) unsigned int*)l, 16, 0, 0);
}

#define SCALE_QK 0.17677669529663687f  // 1/sqrt(32)

// extra work rider for GEMM dispatches (blocks beyond the tile grid)
struct Extra {
    int mode;  // 0 = none, 1 = relay5 (32 blocks), 2 = rep_part (512 blocks)
    const float* relay;
    const float* W[5];
    const float* bvec[5];
    float* out5[5];
    const float* nodes;
    const int* dmask;
    float* part;
};

// ---------- setup kernel: weight transposes (+ emb transpose, + RELAY zero) ----------
__global__ __launch_bounds__(256) void transpose_many(const float* __restrict__ w0,
                                                      const float* __restrict__ w1,
                                                      const float* __restrict__ w2,
                                                      const float* __restrict__ w3,
                                                      const float* __restrict__ w4,
                                                      const float* __restrict__ wemb,
                                                      unsigned short* __restrict__ out,
                                                      unsigned short* __restrict__ outEmb,
                                                      float* __restrict__ relayAcc) {
    __shared__ float tile[64][65];
    int m = blockIdx.y;
    int tid = threadIdx.x;
    if (m == 30) {
#pragma unroll
        for (int i = 0; i < 20; i++) {
            int e = i * 4096 + blockIdx.x * 256 + tid;  // 0..81919
            int n = e / 320, k = e - n * 320;
            outEmb[e] = (k < 300) ? f2b(wemb[k * 256 + n]) : (unsigned short)0;
        }
        if (blockIdx.x == 0) {
#pragma unroll
            for (int j = 0; j < 32; j++) relayAcc[j * 256 + tid] = 0.f;
        }
        return;
    }
    int fam = m / 6, it = m % 6;
    const float* src =
        (fam == 0 ? w0 : fam == 1 ? w1 : fam == 2 ? w2 : fam == 3 ? w3 : w4) + it * 65536;
    unsigned short* dst = out + (size_t)(it * 5 + fam) * 65536;
    int k0 = (blockIdx.x & 3) * 64, n0 = (blockIdx.x >> 2) * 64;
    int rg = tid >> 6, cl = tid & 63;
#pragma unroll
    for (int i = 0; i < 16; i++) {
        int kl = rg * 16 + i;
        tile[kl][cl] = src[(k0 + kl) * 256 + n0 + cl];
    }
    __syncthreads();
#pragma unroll
    for (int i = 0; i < 16; i++) {
        int nl = rg * 16 + i;
        dst[(n0 + nl) * 256 + k0 + cl] = f2b(tile[cl][nl]);
    }
}

// gather emb rows (f32) into padded bf16 A [16384, 320]
__global__ void gather_emb(const int* __restrict__ data,
                           const float* __restrict__ emb,
                           unsigned short* __restrict__ apad) {
    int row = blockIdx.x;
    int tok = data[row];
    const float* er = emb + (size_t)tok * 300;
    for (int c = threadIdx.x; c < 320; c += 256)
        apad[(size_t)row * 320 + c] = (c < 300) ? f2b(er[c]) : (unsigned short)0;
}

// ---------- MFMA GEMM: single-stage BK=K, global_load_lds, XOR-swizzled LDS ----------
// 1D grid, XCD-aware decode; blocks >= 8*NC*32 run Extra rider work.
// EPI 0: N=512 fused pair -> two bf16 outputs, LDS-bounced coalesced 16B stores
// EPI 1: N=256, resid: r = maskedRead(outF) + leaky(c); outF=r (f32), outB0=f2b(r)
// EPI 2: N=256, store f32 + pos; column-sum/512 atomically into relayAcc (mean fold-in)
template <int EPI, int KDIM, int NC>
__global__ __launch_bounds__(256) void gemm_k(const unsigned short* __restrict__ A,
                                              const unsigned short* __restrict__ Bt,
                                              const float* __restrict__ bias0,
                                              const float* __restrict__ bias1,
                                              float* __restrict__ outF,
                                              unsigned short* __restrict__ outB0,
                                              unsigned short* __restrict__ outB1,
                                              const float* __restrict__ pos,
                                              const int* __restrict__ dmask,
                                              int applyMask,
                                              float* __restrict__ relayAcc,
                                              Extra ex) {
    constexpr int G = KDIM / 8;
    constexpr int NT = 8 * NC * 32;  // tile count
    __shared__ unsigned short Asm[64 * KDIM];
    __shared__ unsigned short Bsm[64 * KDIM];
    const int tid = threadIdx.x;
    const int id = blockIdx.x;
    if (id >= NT) {
        int e = id - NT;
        if (ex.mode == 1) {
            // relay5: one block per batch e; 5 matvecs of [256]x[256,256]
            float* rs = (float*)Asm;
            rs[tid] = ex.relay[e * 256 + tid];
            __syncthreads();
#pragma unroll
            for (int f = 0; f < 5; f++) {
                const float* W = ex.W[f];
                float s = 0.f;
#pragma unroll 8
                for (int k = 0; k < 256; k++) s += rs[k] * W[k * 256 + tid];
                ex.out5[f][e * 256 + tid] = s + ex.bvec[f][tid];
            }
        } else {
            // rep_part: e in [0,512): b=e>>4, c=e&15; masked 32-row max
            int b = e >> 4, c = e & 15;
            const float* p = ex.nodes + ((size_t)b * 512 + c * 32) * 256 + tid;
            const int* dd = ex.dmask + b * 512 + c * 32;
            float m = -1e30f;
            for (int l = 0; l < 32; l++) {
                float v = (dd[l] == 1) ? 0.f : p[l * 256];
                m = fmaxf(m, v);
            }
            ex.part[(b * 16 + c) * 256 + tid] = m;
        }
        return;
    }
    const int wave = tid >> 6, lane = tid & 63;
    const int wm = (wave >> 1) * 32, wn = (wave & 1) * 32;
    const int quad = lane >> 4, l16 = lane & 15;
    const int xcd = id & 7, t = id >> 3;
    const int cIdx = t % NC, rhi = t / NC;
    const int rowBase = (rhi * 8 + xcd) * 64, colBase = cIdx * 64;
    {
        const unsigned short* gbA = A + (size_t)(rowBase + wave * 16) * KDIM;
        const unsigned short* gbB = Bt + (size_t)(colBase + wave * 16) * KDIM;
        unsigned short* lbA = Asm + wave * 16 * KDIM;
        unsigned short* lbB = Bsm + wave * 16 * KDIM;
#pragma unroll
        for (int c = 0; c < G / 4; c++) {
            int gi = c * 64 + lane;
            int rl = gi / G, sl = gi - rl * G;
            int sg = sl ^ (rl & 7);
            gl_lds16(gbA + rl * KDIM + sg * 8, lbA + gi * 8);
            gl_lds16(gbB + rl * KDIM + sg * 8, lbB + gi * 8);
        }
    }
    __syncthreads();

    floatx4 acc[2][2] = {};
    const int mr0 = wm + l16, mr1 = wm + 16 + l16;
    const int nr0 = wn + l16, nr1 = wn + 16 + l16;
#pragma unroll
    for (int ks = 0; ks < KDIM / 32; ks++) {
        int g = ks * 4 + quad;
        bf16x8 af0 = __builtin_bit_cast(bf16x8, *(const ushort8*)&Asm[mr0 * KDIM + ((g ^ (mr0 & 7)) * 8)]);
        bf16x8 af1 = __builtin_bit_cast(bf16x8, *(const ushort8*)&Asm[mr1 * KDIM + ((g ^ (mr1 & 7)) * 8)]);
        bf16x8 bf0 = __builtin_bit_cast(bf16x8, *(const ushort8*)&Bsm[nr0 * KDIM + ((g ^ (nr0 & 7)) * 8)]);
        bf16x8 bf1 = __builtin_bit_cast(bf16x8, *(const ushort8*)&Bsm[nr1 * KDIM + ((g ^ (nr1 & 7)) * 8)]);
        acc[0][0] = __builtin_amdgcn_mfma_f32_16x16x32_bf16(af0, bf0, acc[0][0], 0, 0, 0);
        acc[0][1] = __builtin_amdgcn_mfma_f32_16x16x32_bf16(af0, bf1, acc[0][1], 0, 0, 0);
        acc[1][0] = __builtin_amdgcn_mfma_f32_16x16x32_bf16(af1, bf0, acc[1][0], 0, 0, 0);
        acc[1][1] = __builtin_amdgcn_mfma_f32_16x16x32_bf16(af1, bf1, acc[1][1], 0, 0, 0);
    }
    if (EPI == 0) {
        const int group = colBase >> 8;
        const float* bias = group ? bias1 : bias0;
        unsigned short* obf = group ? outB1 : outB0;
        unsigned short* tile = Asm;
        __syncthreads();
#pragma unroll
        for (int tm = 0; tm < 2; tm++) {
#pragma unroll
            for (int tn = 0; tn < 2; tn++) {
                int lcl = wn + tn * 16 + l16;
                float bv = bias[(colBase & 255) + lcl];
#pragma unroll
                for (int r = 0; r < 4; r++) {
                    int rl = wm + tm * 16 + quad * 4 + r;
                    tile[rl * 72 + lcl] = f2b(acc[tm][tn][r] + bv);
                }
            }
        }
        __syncthreads();
#pragma unroll
        for (int j = 0; j < 2; j++) {
            int c = j * 256 + tid;
            int rl = c >> 3, c8 = c & 7;
            ushort8 v = *(const ushort8*)&tile[rl * 72 + c8 * 8];
            *(ushort8*)(obf + (size_t)(rowBase + rl) * 256 + (colBase & 255) + c8 * 8) = v;
        }
    } else {
#pragma unroll
        for (int tm = 0; tm < 2; tm++) {
#pragma unroll
            for (int tn = 0; tn < 2; tn++) {
                int col = colBase + wn + tn * 16 + l16;
                int lc = col & 255;
                float bv = bias0[lc];
                float cs = 0.f;
#pragma unroll
                for (int r = 0; r < 4; r++) {
                    int row = rowBase + wm + tm * 16 + quad * 4 + r;
                    float c = acc[tm][tn][r] + bv;
                    size_t o = (size_t)row * 256 + lc;
                    if (EPI == 1) {
                        float v = c > 0.f ? c : 0.01f * c;
                        float base = outF[o];
                        if (applyMask && dmask[row] == 1) base = 0.f;
                        float rr = base + v;
                        outF[o] = rr;
                        outB0[o] = f2b(rr);
                    } else {
                        float v = c + pos[(row & 511) * 256 + lc];
                        outF[o] = v;
                        cs += v;
                    }
                }
                if (EPI == 2) {
                    cs += __shfl_xor(cs, 16);
                    cs += __shfl_xor(cs, 32);
                    if (quad == 0)
                        atomicAdd(&relayAcc[(rowBase >> 9) * 256 + lc], cs * (1.f / 512.f));
                }
            }
        }
    }
}

// ---------- wave-level layernorm: one row per wave, shuffle-only, grid 4096 ----------
__global__ __launch_bounds__(256) void ln_k(const float* __restrict__ nodes,
                                            const float* __restrict__ g,
                                            const float* __restrict__ bb,
                                            unsigned short* __restrict__ out,
                                            const int* __restrict__ dmask,
                                            int applyMask) {
    int wave = threadIdx.x >> 6, lane = threadIdx.x & 63;
    int row = blockIdx.x * 4 + wave;
    float4 x = *(const float4*)(nodes + (size_t)row * 256 + lane * 4);
    if (applyMask && dmask[row] == 1) { x.x = 0.f; x.y = 0.f; x.z = 0.f; x.w = 0.f; }
    float s = x.x + x.y + x.z + x.w;
    float q = x.x * x.x + x.y * x.y + x.z * x.z + x.w * x.w;
#pragma unroll
    for (int o = 32; o; o >>= 1) { s += __shfl_xor(s, o); q += __shfl_xor(q, o); }
    float mu = s * (1.f / 256.f);
    float var = q * (1.f / 256.f) - mu * mu;
    float inv = rsqrtf(fmaxf(var, 0.f) + 1e-5f);
    float4 gv = *(const float4*)(g + lane * 4);
    float4 bv = *(const float4*)(bb + lane * 4);
    ushort4 r4;
    r4.x = f2b(gv.x * (x.x - mu) * inv + bv.x);
    r4.y = f2b(gv.y * (x.y - mu) * inv + bv.y);
    r4.z = f2b(gv.z * (x.z - mu) * inv + bv.z);
    r4.w = f2b(gv.w * (x.w - mu) * inv + bv.w);
    *(ushort4*)(out + (size_t)row * 256 + lane * 4) = r4;
}

// ---------- msa1 attention (1 wave per row, 4 cols/lane), XCD-contiguous rows ----------
__global__ __launch_bounds__(256) void attn1_k(const unsigned short* __restrict__ q,
                                               const unsigned short* __restrict__ k,
                                               const float* __restrict__ ak,
                                               const float* __restrict__ av,
                                               unsigned short* __restrict__ att) {
    int tid = threadIdx.x;
    int nb = (blockIdx.x & 7) * 512 + (blockIdx.x >> 3);
    int row = nb * 4 + (tid >> 6);
    int b = row >> 9, l = row & 511;
    int t = tid & 63;
    size_t o = (size_t)row * 256 + t * 4;
    ushort4 z4; z4.x = z4.y = z4.z = z4.w = 0;
    ushort4 q4 = *(const ushort4*)(q + o);
    ushort4 k04 = *(const ushort4*)(k + o);
    ushort4 km4 = (l > 0) ? *(const ushort4*)(k + o - 256) : z4;
    ushort4 kp4 = (l < 511) ? *(const ushort4*)(k + o + 256) : z4;
    float4 akv = *(const float4*)(ak + b * 256 + t * 4);
    float4 avv = *(const float4*)(av + b * 256 + t * 4);
    float qv0 = b2f(q4.x), qv1 = b2f(q4.y), qv2 = b2f(q4.z), qv3 = b2f(q4.w);
    float k00 = b2f(k04.x), k01 = b2f(k04.y), k02 = b2f(k04.z), k03 = b2f(k04.w);
    float km0 = b2f(km4.x), km1 = b2f(km4.y), km2 = b2f(km4.z), km3 = b2f(km4.w);
    float kp0 = b2f(kp4.x), kp1 = b2f(kp4.y), kp2 = b2f(kp4.z), kp3 = b2f(kp4.w);
    float s0 = qv0 * akv.x + qv1 * akv.y + qv2 * akv.z + qv3 * akv.w;
    float s1 = qv0 * km0 + qv1 * km1 + qv2 * km2 + qv3 * km3;
    float s2 = qv0 * k00 + qv1 * k01 + qv2 * k02 + qv3 * k03;
    float s3 = qv0 * kp0 + qv1 * kp1 + qv2 * kp2 + qv3 * kp3;
#pragma unroll
    for (int off = 4; off; off >>= 1) {
        s0 += __shfl_xor(s0, off);
        s1 += __shfl_xor(s1, off);
        s2 += __shfl_xor(s2, off);
        s3 += __shfl_xor(s3, off);
    }
    s0 *= SCALE_QK; s1 *= SCALE_QK; s2 *= SCALE_QK; s3 *= SCALE_QK;
    float m = fmaxf(fmaxf(s0, s1), fmaxf(s2, s3));
    float e0 = __expf(s0 - m), e1 = __expf(s1 - m), e2 = __expf(s2 - m), e3 = __expf(s3 - m);
    float iZ = 1.f / (e0 + e1 + e2 + e3);
    ushort4 r4;
    r4.x = f2b((e0 * avv.x + e1 * km0 + e2 * k00 + e3 * kp0) * iZ);
    r4.y = f2b((e0 * avv.y + e1 * km1 + e2 * k01 + e3 * kp1) * iZ);
    r4.z = f2b((e0 * avv.z + e1 * km2 + e2 * k02 + e3 * kp2) * iZ);
    r4.w = f2b((e0 * avv.w + e1 * km3 + e2 * k03 + e3 * kp3) * iZ);
    *(ushort4*)(att + o) = r4;
}

// ---------- msa2 attention: per (b, head), 513 keys; 512 threads; b128 K loads ----------
__global__ __launch_bounds__(512) void attn2_k(const float* __restrict__ q2,
                                               const unsigned short* __restrict__ k2,
                                               const unsigned short* __restrict__ v2,
                                               const float* __restrict__ rk2,
                                               const float* __restrict__ rv2,
                                               float* __restrict__ att2) {
    __shared__ float sc[513];
    __shared__ float qs[32];
    __shared__ float red[16];
    __shared__ float red2[512];
    int bn = blockIdx.x;
    int b = bn >> 3, n = bn & 7;
    int t = threadIdx.x;
    if (t < 32) qs[t] = q2[b * 256 + n * 32 + t];
    __syncthreads();
    float lmax = -1e30f;
    for (int li = t; li < 513; li += 512) {
        float d = 0.f;
        if (li == 0) {
            const float* kr = rk2 + b * 256 + n * 32;
#pragma unroll 8
            for (int j = 0; j < 32; j++) d += qs[j] * kr[j];
        } else {
            const ushort8* kr8 = (const ushort8*)(k2 + ((size_t)(b * 512 + li - 1) * 256 + n * 32));
#pragma unroll
            for (int jj = 0; jj < 4; jj++) {
                ushort8 v = kr8[jj];
                d += qs[jj * 8 + 0] * b2f(v[0]) + qs[jj * 8 + 1] * b2f(v[1]) +
                     qs[jj * 8 + 2] * b2f(v[2]) + qs[jj * 8 + 3] * b2f(v[3]) +
                     qs[jj * 8 + 4] * b2f(v[4]) + qs[jj * 8 + 5] * b2f(v[5]) +
                     qs[jj * 8 + 6] * b2f(v[6]) + qs[jj * 8 + 7] * b2f(v[7]);
            }
        }
        d *= SCALE_QK;
        sc[li] = d;
        lmax = fmaxf(lmax, d);
    }
#pragma unroll
    for (int o = 32; o; o >>= 1) lmax = fmaxf(lmax, __shfl_xor(lmax, o));
    if ((t & 63) == 0) red[t >> 6] = lmax;
    __syncthreads();
    float m = red[0];
#pragma unroll
    for (int i = 1; i < 8; i++) m = fmaxf(m, red[i]);
    float lsum = 0.f;
    for (int li = t; li < 513; li += 512) {
        float e = __expf(sc[li] - m);
        sc[li] = e;
        lsum += e;
    }
#pragma unroll
    for (int o = 32; o; o >>= 1) lsum += __shfl_xor(lsum, o);
    if ((t & 63) == 0) red[8 + (t >> 6)] = lsum;
    __syncthreads();
    float Z = red[8];
#pragma unroll
    for (int i = 9; i < 16; i++) Z += red[i];
    int d_ = t & 31, g_ = t >> 5;
    float acc = 0.f;
    for (int li = g_; li < 513; li += 16) {
        if (li == 0) {
            acc += sc[0] * rv2[b * 256 + n * 32 + d_];
        } else {
            acc += sc[li] * b2f(v2[(size_t)(b * 512 + li - 1) * 256 + n * 32 + d_]);
        }
    }
    red2[t] = acc;
    __syncthreads();
    if (t < 32) {
        float s = 0.f;
#pragma unroll
        for (int g = 0; g < 16; g++) s += red2[g * 32 + t];
        att2[b * 256 + n * 32 + t] = s / Z;
    }
}

// ---------- relay output proj + leaky, split-K wide (1024 thr); optional final blend ----------
__global__ __launch_bounds__(1024) void relay_out2(const float* __restrict__ att2,
                           const float* __restrict__ WO, const float* __restrict__ bO,
                           float* __restrict__ relay,
                           const float* __restrict__ part,
                           float* __restrict__ outp,
                           int doFinal) {
    __shared__ float r[256];
    __shared__ float partl[1024];
    int b = blockIdx.x, t = threadIdx.x;
    if (t < 256) r[t] = att2[b * 256 + t];
    __syncthreads();
    int col = t & 255, kc = t >> 8;
    float s = 0.f;
    for (int e = kc * 64; e < kc * 64 + 64; e++) s += r[e] * WO[e * 256 + col];
    partl[t] = s;
    __syncthreads();
    if (kc == 0) {
        float tot = partl[col] + partl[256 + col] + partl[512 + col] + partl[768 + col] + bO[col];
        tot = tot > 0.f ? tot : 0.01f * tot;
        relay[b * 256 + col] = tot;
        if (doFinal) {
            float m = -1e30f;
#pragma unroll
            for (int c = 0; c < 16; c++) m = fmaxf(m, part[(b * 16 + c) * 256 + col]);
            outp[b * 256 + col] = 0.5f * m + 0.5f * tot;
        }
    }
}

// ---------- launch ----------
extern "C" void kernel_launch(void* const* d_in, const int* in_sizes, int n_in,
                              void* d_out, int out_size, void* d_ws, size_t ws_size,
                              hipStream_t stream) {
    const int* data = (const int*)d_in[0];
    const float* emb = (const float*)d_in[1];
    const float* emb_fc_W = (const float*)d_in[2];
    const float* emb_fc_b = (const float*)d_in[3];
    const float* pos_emb = (const float*)d_in[4];
    const float* ln_g = (const float*)d_in[5];
    const float* ln_b = (const float*)d_in[6];
    const float* r_WQ = (const float*)d_in[7];
    const float* r_bQ = (const float*)d_in[8];
    const float* r_WK = (const float*)d_in[9];
    const float* r_bK = (const float*)d_in[10];
    const float* r_WV = (const float*)d_in[11];
    const float* r_bV = (const float*)d_in[12];
    const float* r_WO = (const float*)d_in[13];
    const float* r_bO = (const float*)d_in[14];
    const float* s_WQ = (const float*)d_in[15];
    const float* s_bQ = (const float*)d_in[16];
    const float* s_WK = (const float*)d_in[17];
    const float* s_bK = (const float*)d_in[18];
    const float* s_WV = (const float*)d_in[19];
    const float* s_bV = (const float*)d_in[20];
    const float* s_WO = (const float*)d_in[21];
    const float* s_bO = (const float*)d_in[22];

    char* w = (char*)d_ws;
    size_t off = 0;
    auto alloc = [&](size_t bytes) -> char* {
        char* p = w + off;
        off += (bytes + 255) & ~(size_t)255;
        return p;
    };
    float* RELAY = (float*)alloc(8192 * 4);
    float* AK = (float*)alloc(8192 * 4);
    float* AV = (float*)alloc(8192 * 4);
    float* Q2 = (float*)alloc(8192 * 4);
    float* RK2 = (float*)alloc(8192 * 4);
    float* RV2 = (float*)alloc(8192 * 4);
    float* ATT2 = (float*)alloc(8192 * 4);
    float* PART = (float*)alloc((size_t)32 * 16 * 256 * 4);
    unsigned short* WTE = (unsigned short*)alloc((size_t)256 * 320 * 2);
    unsigned short* WT = (unsigned short*)alloc((size_t)30 * 65536 * 2);
    float* NODES = (float*)alloc((size_t)16384 * 256 * 4);
    unsigned short* NLN = (unsigned short*)alloc((size_t)16384 * 256 * 2);
    unsigned short* Qb = (unsigned short*)alloc((size_t)16384 * 256 * 2);
    unsigned short* Kb16 = (unsigned short*)alloc((size_t)16384 * 256 * 2);
    unsigned short* NBF = (unsigned short*)alloc((size_t)16384 * 320 * 2);
    // aliases (lifetimes disjoint):
    unsigned short* AEMB = NBF;   // gather buffer; dead after embed GEMM
    unsigned short* ATT = NLN;    // attn1 out; NLN dead after QK GEMM
    unsigned short* K2b = Qb;     // msa2 K; Qb dead after attn1
    unsigned short* V2b = Kb16;   // msa2 V; Kb dead after attn1

    Extra exNone = {};
    exNone.mode = 0;

    transpose_many<<<dim3(16, 31), 256, 0, stream>>>(r_WQ, r_WK, r_WO, s_WK, s_WV,
                                                     emb_fc_W, WT, WTE, RELAY);
    gather_emb<<<16384, 256, 0, stream>>>(data, emb, AEMB);
    gemm_k<2, 320, 4><<<1024, 256, 0, stream>>>(AEMB, WTE, emb_fc_b, nullptr,
                                                NODES, nullptr, nullptr, pos_emb,
                                                nullptr, 0, RELAY, exNone);

    for (int i = 0; i < 6; i++) {
        const unsigned short* wQK = WT + (size_t)(i * 5 + 0) * 65536;
        const unsigned short* wO = WT + (size_t)(i * 5 + 2) * 65536;
        const unsigned short* wKV2 = WT + (size_t)(i * 5 + 3) * 65536;

        // relay5 rider on the QK GEMM (blocks 2048..2079)
        Extra exR = {};
        exR.mode = 1;
        exR.relay = RELAY;
        exR.W[0] = r_WK + (size_t)i * 65536; exR.bvec[0] = r_bK + i * 256; exR.out5[0] = AK;
        exR.W[1] = r_WV + (size_t)i * 65536; exR.bvec[1] = r_bV + i * 256; exR.out5[1] = AV;
        exR.W[2] = s_WQ + (size_t)i * 65536; exR.bvec[2] = s_bQ + i * 256; exR.out5[2] = Q2;
        exR.W[3] = s_WK + (size_t)i * 65536; exR.bvec[3] = s_bK + i * 256; exR.out5[3] = RK2;
        exR.W[4] = s_WV + (size_t)i * 65536; exR.bvec[4] = s_bV + i * 256; exR.out5[4] = RV2;

        ln_k<<<4096, 256, 0, stream>>>(NODES, ln_g + i * 256, ln_b + i * 256, NLN, data, i > 0);
        gemm_k<0, 256, 8><<<2080, 256, 0, stream>>>(NLN, wQK, r_bQ + i * 256, r_bK + i * 256,
                                                    nullptr, Qb, Kb16, nullptr, nullptr, 0,
                                                    nullptr, exR);
        attn1_k<<<4096, 256, 0, stream>>>(Qb, Kb16, AK, AV, ATT);
        gemm_k<1, 256, 4><<<1024, 256, 0, stream>>>(ATT, wO, r_bO + i * 256, nullptr,
                                                    NODES, NBF, nullptr, nullptr, data, i > 0,
                                                    nullptr, exNone);
        if (i == 5) {
            // rep_part rider on the final KV2 GEMM (blocks 2048..2559)
            Extra exP = {};
            exP.mode = 2;
            exP.nodes = NODES;
            exP.dmask = data;
            exP.part = PART;
            gemm_k<0, 256, 8><<<2560, 256, 0, stream>>>(NBF, wKV2, s_bK + i * 256, s_bV + i * 256,
                                                        nullptr, K2b, V2b, nullptr, nullptr, 0,
                                                        nullptr, exP);
        } else {
            gemm_k<0, 256, 8><<<2048, 256, 0, stream>>>(NBF, wKV2, s_bK + i * 256, s_bV + i * 256,
                                                        nullptr, K2b, V2b, nullptr, nullptr, 0,
                                                        nullptr, exNone);
        }
        attn2_k<<<256, 512, 0, stream>>>(Q2, K2b, V2b, RK2, RV2, ATT2);
        relay_out2<<<32, 1024, 0, stream>>>(ATT2, s_WO + (size_t)i * 65536, s_bO + i * 256, RELAY,
                                            PART, (float*)d_out, i == 5 ? 1 : 0);
    }
}

// Round 16
// 693.016 us; speedup vs baseline: 1.4081x; 1.4081x over previous
//
#include <hip/hip_runtime.h>
#include <stdint.h>

// ---------- types / helpers ----------
typedef __bf16 bf16x8 __attribute__((ext_vector_type(8)));
typedef unsigned short ushort8 __attribute__((ext_vector_type(8)));
typedef float floatx4 __attribute__((ext_vector_type(4)));

__device__ __forceinline__ unsigned short f2b(float f) {
    unsigned int u = __builtin_bit_cast(unsigned int, f);
    u += 0x7fffu + ((u >> 16) & 1u);
    return (unsigned short)(u >> 16);
}
__device__ __forceinline__ float b2f(unsigned short u) {
    union { unsigned int i; float f; } x; x.i = ((unsigned int)u) << 16; return x.f;
}
// async global->LDS, 16B per lane; dest must be wave-uniform base + lane*16.
__device__ __forceinline__ void gl_lds16(const unsigned short* g, unsigned short* l) {
    __builtin_amdgcn_global_load_lds(
        (const __attribute__((address_space(1))) unsigned int*)g,
        (__attribute__((address_space(3))) unsigned int*)l, 16, 0, 0);
}

#define SCALE_QK 0.17677669529663687f  // 1/sqrt(32)

// ---------- setup kernel: weight transposes (+ emb transpose, + RELAY zero) ----------
__global__ __launch_bounds__(256) void transpose_many(const float* __restrict__ w0,
                                                      const float* __restrict__ w1,
                                                      const float* __restrict__ w2,
                                                      const float* __restrict__ w3,
                                                      const float* __restrict__ w4,
                                                      const float* __restrict__ wemb,
                                                      unsigned short* __restrict__ out,
                                                      unsigned short* __restrict__ outEmb,
                                                      float* __restrict__ relayAcc) {
    __shared__ float tile[64][65];
    int m = blockIdx.y;
    int tid = threadIdx.x;
    if (m == 30) {
#pragma unroll
        for (int i = 0; i < 20; i++) {
            int e = i * 4096 + blockIdx.x * 256 + tid;  // 0..81919
            int n = e / 320, k = e - n * 320;
            outEmb[e] = (k < 300) ? f2b(wemb[k * 256 + n]) : (unsigned short)0;
        }
        if (blockIdx.x == 0) {
#pragma unroll
            for (int j = 0; j < 32; j++) relayAcc[j * 256 + tid] = 0.f;
        }
        return;
    }
    int fam = m / 6, it = m % 6;
    const float* src =
        (fam == 0 ? w0 : fam == 1 ? w1 : fam == 2 ? w2 : fam == 3 ? w3 : w4) + it * 65536;
    unsigned short* dst = out + (size_t)(it * 5 + fam) * 65536;
    int k0 = (blockIdx.x & 3) * 64, n0 = (blockIdx.x >> 2) * 64;
    int rg = tid >> 6, cl = tid & 63;
#pragma unroll
    for (int i = 0; i < 16; i++) {
        int kl = rg * 16 + i;
        tile[kl][cl] = src[(k0 + kl) * 256 + n0 + cl];
    }
    __syncthreads();
#pragma unroll
    for (int i = 0; i < 16; i++) {
        int nl = rg * 16 + i;
        dst[(n0 + nl) * 256 + k0 + cl] = f2b(tile[cl][nl]);
    }
}

// gather emb rows (f32) into padded bf16 A [16384, 320]
__global__ void gather_emb(const int* __restrict__ data,
                           const float* __restrict__ emb,
                           unsigned short* __restrict__ apad) {
    int row = blockIdx.x;
    int tok = data[row];
    const float* er = emb + (size_t)tok * 300;
    for (int c = threadIdx.x; c < 320; c += 256)
        apad[(size_t)row * 320 + c] = (c < 300) ? f2b(er[c]) : (unsigned short)0;
}

// ---------- MFMA GEMM: single-stage BK=K, global_load_lds, XOR-swizzled LDS ----------
// 1D grid, XCD-aware decode (R11-validated).
// EPI 0: N=512 fused pair -> two bf16 outputs, LDS-bounced coalesced 16B stores
// EPI 1: N=256, resid: r = maskedRead(outF) + leaky(c); outF=r (f32), outB0=f2b(r)
// EPI 2: N=256, store f32 + pos; column-sum/512 atomically into relayAcc (mean fold-in)
template <int EPI, int KDIM, int NC>
__global__ __launch_bounds__(256) void gemm_k(const unsigned short* __restrict__ A,
                                              const unsigned short* __restrict__ Bt,
                                              const float* __restrict__ bias0,
                                              const float* __restrict__ bias1,
                                              float* __restrict__ outF,
                                              unsigned short* __restrict__ outB0,
                                              unsigned short* __restrict__ outB1,
                                              const float* __restrict__ pos,
                                              const int* __restrict__ dmask,
                                              int applyMask,
                                              float* __restrict__ relayAcc) {
    constexpr int G = KDIM / 8;
    __shared__ unsigned short Asm[64 * KDIM];
    __shared__ unsigned short Bsm[64 * KDIM];
    const int tid = threadIdx.x;
    const int wave = tid >> 6, lane = tid & 63;
    const int wm = (wave >> 1) * 32, wn = (wave & 1) * 32;
    const int quad = lane >> 4, l16 = lane & 15;
    const int id = blockIdx.x;
    const int xcd = id & 7, t = id >> 3;
    const int cIdx = t % NC, rhi = t / NC;
    const int rowBase = (rhi * 8 + xcd) * 64, colBase = cIdx * 64;
    {
        const unsigned short* gbA = A + (size_t)(rowBase + wave * 16) * KDIM;
        const unsigned short* gbB = Bt + (size_t)(colBase + wave * 16) * KDIM;
        unsigned short* lbA = Asm + wave * 16 * KDIM;
        unsigned short* lbB = Bsm + wave * 16 * KDIM;
#pragma unroll
        for (int c = 0; c < G / 4; c++) {
            int gi = c * 64 + lane;
            int rl = gi / G, sl = gi - rl * G;
            int sg = sl ^ (rl & 7);
            gl_lds16(gbA + rl * KDIM + sg * 8, lbA + gi * 8);
            gl_lds16(gbB + rl * KDIM + sg * 8, lbB + gi * 8);
        }
    }
    __syncthreads();

    floatx4 acc[2][2] = {};
    const int mr0 = wm + l16, mr1 = wm + 16 + l16;
    const int nr0 = wn + l16, nr1 = wn + 16 + l16;
#pragma unroll
    for (int ks = 0; ks < KDIM / 32; ks++) {
        int g = ks * 4 + quad;
        bf16x8 af0 = __builtin_bit_cast(bf16x8, *(const ushort8*)&Asm[mr0 * KDIM + ((g ^ (mr0 & 7)) * 8)]);
        bf16x8 af1 = __builtin_bit_cast(bf16x8, *(const ushort8*)&Asm[mr1 * KDIM + ((g ^ (mr1 & 7)) * 8)]);
        bf16x8 bf0 = __builtin_bit_cast(bf16x8, *(const ushort8*)&Bsm[nr0 * KDIM + ((g ^ (nr0 & 7)) * 8)]);
        bf16x8 bf1 = __builtin_bit_cast(bf16x8, *(const ushort8*)&Bsm[nr1 * KDIM + ((g ^ (nr1 & 7)) * 8)]);
        acc[0][0] = __builtin_amdgcn_mfma_f32_16x16x32_bf16(af0, bf0, acc[0][0], 0, 0, 0);
        acc[0][1] = __builtin_amdgcn_mfma_f32_16x16x32_bf16(af0, bf1, acc[0][1], 0, 0, 0);
        acc[1][0] = __builtin_amdgcn_mfma_f32_16x16x32_bf16(af1, bf0, acc[1][0], 0, 0, 0);
        acc[1][1] = __builtin_amdgcn_mfma_f32_16x16x32_bf16(af1, bf1, acc[1][1], 0, 0, 0);
    }
    if (EPI == 0) {
        const int group = colBase >> 8;
        const float* bias = group ? bias1 : bias0;
        unsigned short* obf = group ? outB1 : outB0;
        unsigned short* tile = Asm;
        __syncthreads();
#pragma unroll
        for (int tm = 0; tm < 2; tm++) {
#pragma unroll
            for (int tn = 0; tn < 2; tn++) {
                int lcl = wn + tn * 16 + l16;
                float bv = bias[(colBase & 255) + lcl];
#pragma unroll
                for (int r = 0; r < 4; r++) {
                    int rl = wm + tm * 16 + quad * 4 + r;
                    tile[rl * 72 + lcl] = f2b(acc[tm][tn][r] + bv);
                }
            }
        }
        __syncthreads();
#pragma unroll
        for (int j = 0; j < 2; j++) {
            int c = j * 256 + tid;
            int rl = c >> 3, c8 = c & 7;
            ushort8 v = *(const ushort8*)&tile[rl * 72 + c8 * 8];
            *(ushort8*)(obf + (size_t)(rowBase + rl) * 256 + (colBase & 255) + c8 * 8) = v;
        }
    } else {
#pragma unroll
        for (int tm = 0; tm < 2; tm++) {
#pragma unroll
            for (int tn = 0; tn < 2; tn++) {
                int col = colBase + wn + tn * 16 + l16;
                int lc = col & 255;
                float bv = bias0[lc];
                float cs = 0.f;
#pragma unroll
                for (int r = 0; r < 4; r++) {
                    int row = rowBase + wm + tm * 16 + quad * 4 + r;
                    float c = acc[tm][tn][r] + bv;
                    size_t o = (size_t)row * 256 + lc;
                    if (EPI == 1) {
                        float v = c > 0.f ? c : 0.01f * c;
                        float base = outF[o];
                        if (applyMask && dmask[row] == 1) base = 0.f;
                        float rr = base + v;
                        outF[o] = rr;
                        outB0[o] = f2b(rr);
                    } else {
                        float v = c + pos[(row & 511) * 256 + lc];
                        outF[o] = v;
                        cs += v;
                    }
                }
                if (EPI == 2) {
                    cs += __shfl_xor(cs, 16);
                    cs += __shfl_xor(cs, 32);
                    if (quad == 0)
                        atomicAdd(&relayAcc[(rowBase >> 9) * 256 + lc], cs * (1.f / 512.f));
                }
            }
        }
    }
}

// ---------- wave-level layernorm: one row per wave, shuffle-only, grid 4096 ----------
__global__ __launch_bounds__(256) void ln_k(const float* __restrict__ nodes,
                                            const float* __restrict__ g,
                                            const float* __restrict__ bb,
                                            unsigned short* __restrict__ out,
                                            const int* __restrict__ dmask,
                                            int applyMask) {
    int wave = threadIdx.x >> 6, lane = threadIdx.x & 63;
    int row = blockIdx.x * 4 + wave;
    float4 x = *(const float4*)(nodes + (size_t)row * 256 + lane * 4);
    if (applyMask && dmask[row] == 1) { x.x = 0.f; x.y = 0.f; x.z = 0.f; x.w = 0.f; }
    float s = x.x + x.y + x.z + x.w;
    float q = x.x * x.x + x.y * x.y + x.z * x.z + x.w * x.w;
#pragma unroll
    for (int o = 32; o; o >>= 1) { s += __shfl_xor(s, o); q += __shfl_xor(q, o); }
    float mu = s * (1.f / 256.f);
    float var = q * (1.f / 256.f) - mu * mu;
    float inv = rsqrtf(fmaxf(var, 0.f) + 1e-5f);
    float4 gv = *(const float4*)(g + lane * 4);
    float4 bv = *(const float4*)(bb + lane * 4);
    ushort4 r4;
    r4.x = f2b(gv.x * (x.x - mu) * inv + bv.x);
    r4.y = f2b(gv.y * (x.y - mu) * inv + bv.y);
    r4.z = f2b(gv.z * (x.z - mu) * inv + bv.z);
    r4.w = f2b(gv.w * (x.w - mu) * inv + bv.w);
    *(ushort4*)(out + (size_t)row * 256 + lane * 4) = r4;
}

// ---------- relay matvecs, split-K wide blocks (1024 thr), grid (32,5) ----------
__global__ __launch_bounds__(1024) void relay5(const float* __restrict__ relay,
                       const float* __restrict__ rWK, const float* __restrict__ rbK,
                       const float* __restrict__ rWV, const float* __restrict__ rbV,
                       const float* __restrict__ sWQ, const float* __restrict__ sbQ,
                       const float* __restrict__ sWK, const float* __restrict__ sbK,
                       const float* __restrict__ sWV, const float* __restrict__ sbV,
                       float* __restrict__ AK, float* __restrict__ AV,
                       float* __restrict__ Q2, float* __restrict__ RK2, float* __restrict__ RV2) {
    __shared__ float r[256];
    __shared__ float part[1024];
    int b = blockIdx.x, fam = blockIdx.y, t = threadIdx.x;
    if (t < 256) r[t] = relay[b * 256 + t];
    __syncthreads();
    const float* W; const float* bi; float* o;
    switch (fam) {
        case 0: W = rWK; bi = rbK; o = AK; break;
        case 1: W = rWV; bi = rbV; o = AV; break;
        case 2: W = sWQ; bi = sbQ; o = Q2; break;
        case 3: W = sWK; bi = sbK; o = RK2; break;
        default: W = sWV; bi = sbV; o = RV2; break;
    }
    int col = t & 255, kc = t >> 8;
    float s = 0.f;
    for (int e = kc * 64; e < kc * 64 + 64; e++) s += r[e] * W[e * 256 + col];
    part[t] = s;
    __syncthreads();
    if (kc == 0)
        o[b * 256 + col] = part[col] + part[256 + col] + part[512 + col] + part[768 + col] + bi[col];
}

// ---------- msa1 attention (1 wave per row, 4 cols/lane), XCD-contiguous rows ----------
__global__ __launch_bounds__(256) void attn1_k(const unsigned short* __restrict__ q,
                                               const unsigned short* __restrict__ k,
                                               const float* __restrict__ ak,
                                               const float* __restrict__ av,
                                               unsigned short* __restrict__ att) {
    int tid = threadIdx.x;
    int nb = (blockIdx.x & 7) * 512 + (blockIdx.x >> 3);
    int row = nb * 4 + (tid >> 6);
    int b = row >> 9, l = row & 511;
    int t = tid & 63;
    size_t o = (size_t)row * 256 + t * 4;
    ushort4 z4; z4.x = z4.y = z4.z = z4.w = 0;
    ushort4 q4 = *(const ushort4*)(q + o);
    ushort4 k04 = *(const ushort4*)(k + o);
    ushort4 km4 = (l > 0) ? *(const ushort4*)(k + o - 256) : z4;
    ushort4 kp4 = (l < 511) ? *(const ushort4*)(k + o + 256) : z4;
    float4 akv = *(const float4*)(ak + b * 256 + t * 4);
    float4 avv = *(const float4*)(av + b * 256 + t * 4);
    float qv0 = b2f(q4.x), qv1 = b2f(q4.y), qv2 = b2f(q4.z), qv3 = b2f(q4.w);
    float k00 = b2f(k04.x), k01 = b2f(k04.y), k02 = b2f(k04.z), k03 = b2f(k04.w);
    float km0 = b2f(km4.x), km1 = b2f(km4.y), km2 = b2f(km4.z), km3 = b2f(km4.w);
    float kp0 = b2f(kp4.x), kp1 = b2f(kp4.y), kp2 = b2f(kp4.z), kp3 = b2f(kp4.w);
    float s0 = qv0 * akv.x + qv1 * akv.y + qv2 * akv.z + qv3 * akv.w;
    float s1 = qv0 * km0 + qv1 * km1 + qv2 * km2 + qv3 * km3;
    float s2 = qv0 * k00 + qv1 * k01 + qv2 * k02 + qv3 * k03;
    float s3 = qv0 * kp0 + qv1 * kp1 + qv2 * kp2 + qv3 * kp3;
#pragma unroll
    for (int off = 4; off; off >>= 1) {
        s0 += __shfl_xor(s0, off);
        s1 += __shfl_xor(s1, off);
        s2 += __shfl_xor(s2, off);
        s3 += __shfl_xor(s3, off);
    }
    s0 *= SCALE_QK; s1 *= SCALE_QK; s2 *= SCALE_QK; s3 *= SCALE_QK;
    float m = fmaxf(fmaxf(s0, s1), fmaxf(s2, s3));
    float e0 = __expf(s0 - m), e1 = __expf(s1 - m), e2 = __expf(s2 - m), e3 = __expf(s3 - m);
    float iZ = 1.f / (e0 + e1 + e2 + e3);
    ushort4 r4;
    r4.x = f2b((e0 * avv.x + e1 * km0 + e2 * k00 + e3 * kp0) * iZ);
    r4.y = f2b((e0 * avv.y + e1 * km1 + e2 * k01 + e3 * kp1) * iZ);
    r4.z = f2b((e0 * avv.z + e1 * km2 + e2 * k02 + e3 * kp2) * iZ);
    r4.w = f2b((e0 * avv.w + e1 * km3 + e2 * k03 + e3 * kp3) * iZ);
    *(ushort4*)(att + o) = r4;
}

// ---------- msa2 attention: per (b, head), 513 keys; 512 threads; b128 K loads ----------
__global__ __launch_bounds__(512) void attn2_k(const float* __restrict__ q2,
                                               const unsigned short* __restrict__ k2,
                                               const unsigned short* __restrict__ v2,
                                               const float* __restrict__ rk2,
                                               const float* __restrict__ rv2,
                                               float* __restrict__ att2) {
    __shared__ float sc[513];
    __shared__ float qs[32];
    __shared__ float red[16];
    __shared__ float red2[512];
    int bn = blockIdx.x;
    int b = bn >> 3, n = bn & 7;
    int t = threadIdx.x;
    if (t < 32) qs[t] = q2[b * 256 + n * 32 + t];
    __syncthreads();
    float lmax = -1e30f;
    for (int li = t; li < 513; li += 512) {
        float d = 0.f;
        if (li == 0) {
            const float* kr = rk2 + b * 256 + n * 32;
#pragma unroll 8
            for (int j = 0; j < 32; j++) d += qs[j] * kr[j];
        } else {
            const ushort8* kr8 = (const ushort8*)(k2 + ((size_t)(b * 512 + li - 1) * 256 + n * 32));
#pragma unroll
            for (int jj = 0; jj < 4; jj++) {
                ushort8 v = kr8[jj];
                d += qs[jj * 8 + 0] * b2f(v[0]) + qs[jj * 8 + 1] * b2f(v[1]) +
                     qs[jj * 8 + 2] * b2f(v[2]) + qs[jj * 8 + 3] * b2f(v[3]) +
                     qs[jj * 8 + 4] * b2f(v[4]) + qs[jj * 8 + 5] * b2f(v[5]) +
                     qs[jj * 8 + 6] * b2f(v[6]) + qs[jj * 8 + 7] * b2f(v[7]);
            }
        }
        d *= SCALE_QK;
        sc[li] = d;
        lmax = fmaxf(lmax, d);
    }
#pragma unroll
    for (int o = 32; o; o >>= 1) lmax = fmaxf(lmax, __shfl_xor(lmax, o));
    if ((t & 63) == 0) red[t >> 6] = lmax;
    __syncthreads();
    float m = red[0];
#pragma unroll
    for (int i = 1; i < 8; i++) m = fmaxf(m, red[i]);
    float lsum = 0.f;
    for (int li = t; li < 513; li += 512) {
        float e = __expf(sc[li] - m);
        sc[li] = e;
        lsum += e;
    }
#pragma unroll
    for (int o = 32; o; o >>= 1) lsum += __shfl_xor(lsum, o);
    if ((t & 63) == 0) red[8 + (t >> 6)] = lsum;
    __syncthreads();
    float Z = red[8];
#pragma unroll
    for (int i = 9; i < 16; i++) Z += red[i];
    int d_ = t & 31, g_ = t >> 5;
    float acc = 0.f;
    for (int li = g_; li < 513; li += 16) {
        if (li == 0) {
            acc += sc[0] * rv2[b * 256 + n * 32 + d_];
        } else {
            acc += sc[li] * b2f(v2[(size_t)(b * 512 + li - 1) * 256 + n * 32 + d_]);
        }
    }
    red2[t] = acc;
    __syncthreads();
    if (t < 32) {
        float s = 0.f;
#pragma unroll
        for (int g = 0; g < 16; g++) s += red2[g * 32 + t];
        att2[b * 256 + n * 32 + t] = s / Z;
    }
}

// ---------- relay output proj + leaky, split-K wide (1024 thr) ----------
__global__ __launch_bounds__(1024) void relay_out2(const float* __restrict__ att2,
                           const float* __restrict__ WO, const float* __restrict__ bO,
                           float* __restrict__ relay) {
    __shared__ float r[256];
    __shared__ float part[1024];
    int b = blockIdx.x, t = threadIdx.x;
    if (t < 256) r[t] = att2[b * 256 + t];
    __syncthreads();
    int col = t & 255, kc = t >> 8;
    float s = 0.f;
    for (int e = kc * 64; e < kc * 64 + 64; e++) s += r[e] * WO[e * 256 + col];
    part[t] = s;
    __syncthreads();
    if (kc == 0) {
        float tot = part[col] + part[256 + col] + part[512 + col] + part[768 + col] + bO[col];
        relay[b * 256 + col] = tot > 0.f ? tot : 0.01f * tot;
    }
}

// ---------- rep: two-phase masked max + blend ----------
__global__ void rep_part(const float* __restrict__ nodes, const int* __restrict__ dmask,
                         float* __restrict__ part) {
    int b = blockIdx.x, c = blockIdx.y, h = threadIdx.x;
    const float* p = nodes + ((size_t)b * 512 + c * 32) * 256 + h;
    const int* dd = dmask + b * 512 + c * 32;
    float m = -1e30f;
    for (int l = 0; l < 32; l++) {
        float v = (dd[l] == 1) ? 0.f : p[l * 256];
        m = fmaxf(m, v);
    }
    part[(b * 16 + c) * 256 + h] = m;
}
__global__ void rep_comb(const float* __restrict__ part, const float* __restrict__ relay,
                         float* __restrict__ out) {
    int b = blockIdx.x, h = threadIdx.x;
    float m = -1e30f;
    for (int c = 0; c < 16; c++) m = fmaxf(m, part[(b * 16 + c) * 256 + h]);
    out[b * 256 + h] = 0.5f * m + 0.5f * relay[b * 256 + h];
}

// ---------- launch ----------
extern "C" void kernel_launch(void* const* d_in, const int* in_sizes, int n_in,
                              void* d_out, int out_size, void* d_ws, size_t ws_size,
                              hipStream_t stream) {
    const int* data = (const int*)d_in[0];
    const float* emb = (const float*)d_in[1];
    const float* emb_fc_W = (const float*)d_in[2];
    const float* emb_fc_b = (const float*)d_in[3];
    const float* pos_emb = (const float*)d_in[4];
    const float* ln_g = (const float*)d_in[5];
    const float* ln_b = (const float*)d_in[6];
    const float* r_WQ = (const float*)d_in[7];
    const float* r_bQ = (const float*)d_in[8];
    const float* r_WK = (const float*)d_in[9];
    const float* r_bK = (const float*)d_in[10];
    const float* r_WV = (const float*)d_in[11];
    const float* r_bV = (const float*)d_in[12];
    const float* r_WO = (const float*)d_in[13];
    const float* r_bO = (const float*)d_in[14];
    const float* s_WQ = (const float*)d_in[15];
    const float* s_bQ = (const float*)d_in[16];
    const float* s_WK = (const float*)d_in[17];
    const float* s_bK = (const float*)d_in[18];
    const float* s_WV = (const float*)d_in[19];
    const float* s_bV = (const float*)d_in[20];
    const float* s_WO = (const float*)d_in[21];
    const float* s_bO = (const float*)d_in[22];

    char* w = (char*)d_ws;
    size_t off = 0;
    auto alloc = [&](size_t bytes) -> char* {
        char* p = w + off;
        off += (bytes + 255) & ~(size_t)255;
        return p;
    };
    float* RELAY = (float*)alloc(8192 * 4);
    float* AK = (float*)alloc(8192 * 4);
    float* AV = (float*)alloc(8192 * 4);
    float* Q2 = (float*)alloc(8192 * 4);
    float* RK2 = (float*)alloc(8192 * 4);
    float* RV2 = (float*)alloc(8192 * 4);
    float* ATT2 = (float*)alloc(8192 * 4);
    float* PART = (float*)alloc((size_t)32 * 16 * 256 * 4);
    unsigned short* WTE = (unsigned short*)alloc((size_t)256 * 320 * 2);
    unsigned short* WT = (unsigned short*)alloc((size_t)30 * 65536 * 2);
    float* NODES = (float*)alloc((size_t)16384 * 256 * 4);
    unsigned short* NLN = (unsigned short*)alloc((size_t)16384 * 256 * 2);
    unsigned short* Qb = (unsigned short*)alloc((size_t)16384 * 256 * 2);
    unsigned short* Kb16 = (unsigned short*)alloc((size_t)16384 * 256 * 2);
    unsigned short* NBF = (unsigned short*)alloc((size_t)16384 * 320 * 2);
    // aliases (lifetimes disjoint):
    unsigned short* AEMB = NBF;   // gather buffer; dead after embed GEMM
    unsigned short* ATT = NLN;    // attn1 out; NLN dead after QK GEMM
    unsigned short* K2b = Qb;     // msa2 K; Qb dead after attn1
    unsigned short* V2b = Kb16;   // msa2 V; Kb dead after attn1

    transpose_many<<<dim3(16, 31), 256, 0, stream>>>(r_WQ, r_WK, r_WO, s_WK, s_WV,
                                                     emb_fc_W, WT, WTE, RELAY);
    gather_emb<<<16384, 256, 0, stream>>>(data, emb, AEMB);
    gemm_k<2, 320, 4><<<1024, 256, 0, stream>>>(AEMB, WTE, emb_fc_b, nullptr,
                                                NODES, nullptr, nullptr, pos_emb,
                                                nullptr, 0, RELAY);

    for (int i = 0; i < 6; i++) {
        const unsigned short* wQK = WT + (size_t)(i * 5 + 0) * 65536;
        const unsigned short* wO = WT + (size_t)(i * 5 + 2) * 65536;
        const unsigned short* wKV2 = WT + (size_t)(i * 5 + 3) * 65536;

        ln_k<<<4096, 256, 0, stream>>>(NODES, ln_g + i * 256, ln_b + i * 256, NLN, data, i > 0);
        gemm_k<0, 256, 8><<<2048, 256, 0, stream>>>(NLN, wQK, r_bQ + i * 256, r_bK + i * 256,
                                                    nullptr, Qb, Kb16, nullptr, nullptr, 0,
                                                    nullptr);
        relay5<<<dim3(32, 5), 1024, 0, stream>>>(RELAY,
                                                 r_WK + (size_t)i * 65536, r_bK + i * 256,
                                                 r_WV + (size_t)i * 65536, r_bV + i * 256,
                                                 s_WQ + (size_t)i * 65536, s_bQ + i * 256,
                                                 s_WK + (size_t)i * 65536, s_bK + i * 256,
                                                 s_WV + (size_t)i * 65536, s_bV + i * 256,
                                                 AK, AV, Q2, RK2, RV2);
        attn1_k<<<4096, 256, 0, stream>>>(Qb, Kb16, AK, AV, ATT);
        gemm_k<1, 256, 4><<<1024, 256, 0, stream>>>(ATT, wO, r_bO + i * 256, nullptr,
                                                    NODES, NBF, nullptr, nullptr, data, i > 0,
                                                    nullptr);
        gemm_k<0, 256, 8><<<2048, 256, 0, stream>>>(NBF, wKV2, s_bK + i * 256, s_bV + i * 256,
                                                    nullptr, K2b, V2b, nullptr, nullptr, 0,
                                                    nullptr);
        attn2_k<<<256, 512, 0, stream>>>(Q2, K2b, V2b, RK2, RV2, ATT2);
        relay_out2<<<32, 1024, 0, stream>>>(ATT2, s_WO + (size_t)i * 65536, s_bO + i * 256, RELAY);
    }
    rep_part<<<dim3(32, 16), 256, 0, stream>>>(NODES, data, PART);
    rep_comb<<<32, 256, 0, stream>>>(PART, RELAY, (float*)d_out);
}